// Round 19
// baseline (269.244 us; speedup 1.0000x reference)
//
#include <hip/hip_runtime.h>
#include <hip/hip_fp16.h>

#define N_NODES 307
#define T_LEN   6000
#define L1      5991
#define L2      5982
#define ED      96
#define FDIM    95712
#define NCH2    16
#define LCPC    16                  // l-chunks per channel
#define CHL     376                 // rows per l-chunk (8-aligned; last = 342)
#define NGRP    753                 // octet groups per channel (6024/8)
#define K5CH    (NCH2 * LCPC)       // 256 K-chunks, channel-pure
#define K3L     32                  // K3 outputs per block
#define K3ZP    43                  // z1 halo rows (32 + 11)
#define K3LB    187                 // ceil(5982/32)
#define K3NB    20
#define K3BLKS  (K3LB * K3NB)       // 3740
#define K4ABLK  40                  // K4a blocks (94 rows each)
#define CSUB    8                   // colsum sub-blocks per chunk
#define CSROWS  47                  // rows per colsum sub-block (8*47=376)

// ---- workspace layout (float/u32 offsets) ----
static const size_t WS_P1 = 256;                    // conv1 stat partials: 375*16
static const size_t WS_P2 = 8192;                   // conv2 stat partials: 3740*32
static const size_t WS_P4D = 127872;                // K4a fp64 partials: 40*32 doubles
static const size_t WS_NF = 155648;                 // node_feat 307*96
static const size_t WS_SP = 188416;                 // s_proj
static const size_t WS_RP = 221184;                 // r_proj
static const size_t WS_A2 = 262144;                 // a2k PACKED u32 [16][753][320][8] (K6a fp64 scratch after K5)
static const size_t WS_FP = 262144 + 30842880ull;   // fc partials: 256*96*320  -> 31,105,024
static const size_t WS_BP = 31105024ull + 7864320ull; // packed fcw u32: 95712*96 -> 38,969,344
static const size_t WS_CS2 = 38969344ull + 9188352ull; // colsum partials: 2048*96 -> 48,157,696
// total = 48,354,304 floats ~= 193.4 MB

typedef _Float16 half8 __attribute__((ext_vector_type(8)));
typedef float f32x4 __attribute__((ext_vector_type(4)));

union U4H8 { uint4 u; half8 h; };

// pack fp32 -> (f16 hi | f16 lo<<16), x ~= hi + lo/2048
__device__ __forceinline__ unsigned int pack2h(float x) {
  __half h = __float2half(x);
  float r = (x - __half2float(h)) * 2048.0f;
  __half l = __float2half(r);
  return (unsigned int)__half_as_ushort(h) | ((unsigned int)__half_as_ushort(l) << 16);
}

// split fp32 -> separate f16 hi / f16 lo words
__device__ __forceinline__ void split2h(float x, unsigned short& ho, unsigned short& lo) {
  __half h = __float2half(x);
  float r = (x - __half2float(h)) * 2048.0f;
  __half l = __float2half(r);
  ho = __half_as_ushort(h);
  lo = __half_as_ushort(l);
}

__device__ __forceinline__ void unpackU4(const uint4& a0, const uint4& a1,
                                         U4H8& hi, U4H8& lo) {
  hi.u = make_uint4((a0.x & 0xFFFFu) | (a0.y << 16), (a0.z & 0xFFFFu) | (a0.w << 16),
                    (a1.x & 0xFFFFu) | (a1.y << 16), (a1.z & 0xFFFFu) | (a1.w << 16));
  lo.u = make_uint4((a0.x >> 16) | (a0.y & 0xFFFF0000u), (a0.z >> 16) | (a0.w & 0xFFFF0000u),
                    (a1.x >> 16) | (a1.y & 0xFFFF0000u), (a1.z >> 16) | (a1.w & 0xFFFF0000u));
}

// K5 B-plane LDS swizzle (u16 index): row e (192 u16), XOR k-chunk by e&7.
__device__ __forceinline__ int swz16(int e, int k) {
  return e * 192 + (k ^ ((e & 7) << 3));
}

// ================= K0: zero a2k pad groups (747..752) =================
__global__ __launch_bounds__(256) void dgl_k0_zero(float* __restrict__ ws) {
  unsigned int* a2k = (unsigned int*)(ws + WS_A2);
  int idx = blockIdx.x * 256 + threadIdx.x;   // 61,440 uint4
  int c = idx / 3840, off4 = idx % 3840;
  unsigned int* p = a2k + (((size_t)c * NGRP + 747) * 320) * 8 + (size_t)off4 * 4;
  *(uint4*)p = make_uint4(0u, 0u, 0u, 0u);
}

// ================= K1: conv1 + relu, channel stats only =================
__global__ __launch_bounds__(320) void dgl_k1_conv1_stats(
    const float* __restrict__ nfeat, const float* __restrict__ w1,
    const float* __restrict__ b1, float* __restrict__ ws) {
  __shared__ float sw1[80], sb1[8];
  __shared__ float sred[5][16];
  int tid = threadIdx.x;
  if (tid < 80) sw1[tid] = w1[tid];
  if (tid < 8)  sb1[tid] = b1[tid];
  __syncthreads();
  int l0 = blockIdx.x * 16;
  int n = tid;
  bool nv = n < N_NODES;
  float xx[26];
#pragma unroll
  for (int j = 0; j < 26; ++j) {
    int t = l0 + j;
    xx[j] = (nv && t < T_LEN) ? nfeat[(size_t)t * N_NODES + n] : 0.f;
  }
  float s[8], q[8];
#pragma unroll
  for (int c = 0; c < 8; ++c) { s[c] = 0.f; q[c] = 0.f; }
#pragma unroll
  for (int dl = 0; dl < 16; ++dl) {
    int l = l0 + dl;
    if (nv && l < L1) {
#pragma unroll
      for (int c = 0; c < 8; ++c) {
        float r = sb1[c];
#pragma unroll
        for (int k = 0; k < 10; ++k) r = fmaf(xx[dl + k], sw1[c * 10 + k], r);
        float z = fmaxf(r, 0.f);
        s[c] += z; q[c] += z * z;
      }
    }
  }
  int wv = tid >> 6, ln = tid & 63;
#pragma unroll
  for (int c = 0; c < 8; ++c) {
    float vs = s[c], vq = q[c];
    for (int o = 32; o; o >>= 1) { vs += __shfl_down(vs, o, 64); vq += __shfl_down(vq, o, 64); }
    if (ln == 0) { sred[wv][c] = vs; sred[wv][8 + c] = vq; }
  }
  __syncthreads();
  if (tid < 16) {
    float t = 0.f;
    for (int w = 0; w < 5; ++w) t += sred[w][tid];
    ws[WS_P1 + (size_t)blockIdx.x * 16 + tid] = t;
  }
}

// ================= K2: finalize bn1 =================
__global__ void dgl_k2_fin1(const float* __restrict__ g1, const float* __restrict__ b1,
                            float* __restrict__ ws) {
  __shared__ double sd[16];
  int tid = threadIdx.x;
  if (tid < 16) {
    double a = 0.0;
    for (int j = 0; j < 375; ++j) a += (double)ws[WS_P1 + (size_t)j * 16 + tid];
    sd[tid] = a;
  }
  __syncthreads();
  if (tid < 8) {
    double cnt = (double)N_NODES * (double)L1;
    double m = sd[tid] / cnt;
    double v = sd[tid + 8] / cnt - m * m;
    double inv = 1.0 / sqrt(v + 1e-5);
    ws[tid]     = (float)((double)g1[tid] * inv);
    ws[8 + tid] = (float)((double)b1[tid] - (double)g1[tid] * inv * m);
  }
}

// ================= K3 (MFMA, split planes, reg sliding-window, octet a2k writes) =================
__global__ __launch_bounds__(256, 4) void dgl_k3_conv2(
    const float* __restrict__ nfeat, const float* __restrict__ w1, const float* __restrict__ b1,
    const float* __restrict__ w2, const float* __restrict__ b2, float* __restrict__ ws) {
  __shared__ __align__(16) unsigned short z1h[K3ZP * 128];  // 11 KB
  __shared__ __align__(16) unsigned short z1l[K3ZP * 128];  // 11 KB
  __shared__ __align__(16) unsigned short w2h[16 * 96], w2l[16 * 96];
  __shared__ float sw1[80], sb1[8], ss1[8], st1[8], sb2v[16];
  __shared__ float wps[4][4][4], wpq[4][4][4];
  int tid = threadIdx.x;
  int l0b = blockIdx.x * K3L, n0 = blockIdx.y * 16;
  unsigned int* a2k = (unsigned int*)(ws + WS_A2);

  if (tid < 80) sw1[tid] = w1[tid];
  if (tid < 8)  { sb1[tid] = b1[tid]; ss1[tid] = ws[tid]; st1[tid] = ws[8 + tid]; }
  if (tid < 16) sb2v[tid] = b2[tid];
  for (int i = tid; i < 16 * 96; i += 256) {
    int c2 = i / 96, kk = i % 96;
    float v = (kk < 80) ? w2[c2 * 80 + (kk & 7) * 10 + (kk >> 3)] : 0.f;
    unsigned short ho, lo;
    split2h(v, ho, lo);
    w2h[i] = ho; w2l[i] = lo;
  }
  __syncthreads();
  // z1 build: thread = (n, cin, half); 31-value x-window in registers, sliding FMA
  {
    int n = tid & 15, cin = (tid >> 4) & 7, hf = tid >> 7;
    int lp0 = hf ? 22 : 0;
    int cnt = hf ? 21 : 22;
    int nld = hf ? 30 : 31;
    int nglob0 = n0 + n;
    bool nv = nglob0 < N_NODES;
    float xx[31];
#pragma unroll
    for (int j = 0; j < 31; ++j) {
      int t = l0b + lp0 + j;
      xx[j] = (j < nld && nv && t < T_LEN) ? nfeat[(size_t)t * N_NODES + nglob0] : 0.f;
    }
    float wr[10];
#pragma unroll
    for (int k = 0; k < 10; ++k) wr[k] = sw1[cin * 10 + k];
    float bb = sb1[cin], sc = ss1[cin], sh = st1[cin];
#pragma unroll
    for (int o = 0; o < 22; ++o) {
      if (o < cnt) {
        float r = bb;
#pragma unroll
        for (int k = 0; k < 10; ++k) r = fmaf(xx[o + k], wr[k], r);
        float z = fmaf(sc, fmaxf(r, 0.f), sh);
        unsigned short ho, lo;
        split2h(z, ho, lo);
        int lp = lp0 + o;
        int idx = lp * 128 + ((n ^ (lp & 15)) << 3) + cin;
        z1h[idx] = ho; z1l[idx] = lo;
      }
    }
  }
  __syncthreads();

  int wv = tid >> 6, lane = tid & 63;
  int m = lane & 15, g = lane >> 4;
  U4H8 Ahi[3], Alo[3];
#pragma unroll
  for (int s = 0; s < 3; ++s) {
    Ahi[s].u = *(const uint4*)(&w2h[m * 96 + 32 * s + 8 * g]);
    Alo[s].u = *(const uint4*)(&w2l[m * 96 + 32 * s + 8 * g]);
  }
  float sv[4] = {0.f, 0.f, 0.f, 0.f}, qv[4] = {0.f, 0.f, 0.f, 0.f};
  unsigned int outw[4][8];
  int nglob = n0 + m;
  bool nok = nglob < N_NODES;
#pragma unroll 1
  for (int li = 0; li < 8; ++li) {
    int ll = 8 * wv + li;
    int lg = l0b + ll;
    f32x4 ac1 = (f32x4){0.f, 0.f, 0.f, 0.f};
    f32x4 ac2 = (f32x4){0.f, 0.f, 0.f, 0.f};
#pragma unroll
    for (int s = 0; s < 3; ++s) {
      int lp = ll + 4 * s + g;
      int bpidx = lp * 128 + ((m ^ (lp & 15)) << 3);
      U4H8 Bhi, Blo;
      Bhi.u = *(const uint4*)(&z1h[bpidx]);
      Blo.u = *(const uint4*)(&z1l[bpidx]);
      ac1 = __builtin_amdgcn_mfma_f32_16x16x32_f16(Ahi[s].h, Bhi.h, ac1, 0, 0, 0);
      ac2 = __builtin_amdgcn_mfma_f32_16x16x32_f16(Ahi[s].h, Blo.h, ac2, 0, 0, 0);
      ac2 = __builtin_amdgcn_mfma_f32_16x16x32_f16(Alo[s].h, Bhi.h, ac2, 0, 0, 0);
    }
#pragma unroll
    for (int r = 0; r < 4; ++r) {
      float v = ac1[r] + ac2[r] * (1.0f / 2048.0f) + sb2v[4 * g + r];
      v = fmaxf(v, 0.f);
      if (!nok || lg >= L2) v = 0.f;
      sv[r] += v; qv[r] += v * v;
      outw[r][li] = pack2h(v);
    }
  }
  // octet write: 8 contiguous u32 per (c2, group, n)
  {
    int grp = (l0b + 8 * wv) >> 3;
#pragma unroll
    for (int r = 0; r < 4; ++r) {
      int c2 = 4 * g + r;
      unsigned int* p = a2k + (((size_t)c2 * NGRP + grp) * 320 + nglob) * 8;
      *(uint4*)p = make_uint4(outw[r][0], outw[r][1], outw[r][2], outw[r][3]);
      *(uint4*)(p + 4) = make_uint4(outw[r][4], outw[r][5], outw[r][6], outw[r][7]);
    }
  }
#pragma unroll
  for (int r = 0; r < 4; ++r) {
    for (int o = 1; o < 16; o <<= 1) {
      sv[r] += __shfl_xor(sv[r], o, 64);
      qv[r] += __shfl_xor(qv[r], o, 64);
    }
  }
  if (m == 0) {
#pragma unroll
    for (int r = 0; r < 4; ++r) { wps[wv][g][r] = sv[r]; wpq[wv][g][r] = qv[r]; }
  }
  __syncthreads();
  if (tid < 32) {
    int c2 = tid & 15; bool isq = tid >= 16;
    int gg = c2 >> 2, rr = c2 & 3;
    float t = 0.f;
    for (int w = 0; w < 4; ++w) t += isq ? wpq[w][gg][rr] : wps[w][gg][rr];
    ws[WS_P2 + ((size_t)blockIdx.y * gridDim.x + blockIdx.x) * 32 + tid] = t;
  }
}

// ================= K4a: tree-reduce conv2 stat partials (fp64) =================
__global__ __launch_bounds__(512) void dgl_k4a(float* __restrict__ ws) {
  __shared__ double red[16][32];
  int tid = threadIdx.x, blk = blockIdx.x;
  int v = tid & 31, p = tid >> 5;   // p 0..15
  double a = 0.0;
#pragma unroll
  for (int k = 0; k < 6; ++k) {
    int idx = p + 16 * k;
    int j = blk * 94 + idx;
    if (idx < 94 && j < K3BLKS) a += (double)ws[WS_P2 + (size_t)j * 32 + v];
  }
  red[p][v] = a;
  __syncthreads();
  if (p == 0) {
    double s = 0.0;
    for (int q = 0; q < 16; ++q) s += red[q][v];
    ((double*)(ws + WS_P4D))[(size_t)blk * 32 + v] = s;
  }
}

// ================= K4b2: finalize bn2 from fp64 partials =================
__global__ void dgl_k4b2_fin(const float* __restrict__ g2, const float* __restrict__ b2,
                             float* __restrict__ ws) {
  __shared__ double sd[32];
  int tid = threadIdx.x;
  if (tid < 32) {
    const double* pd = (const double*)(ws + WS_P4D);
    double s = 0.0;
    for (int b = 0; b < K4ABLK; ++b) s += pd[(size_t)b * 32 + tid];
    sd[tid] = s;
  }
  __syncthreads();
  if (tid < 16) {
    double cnt = (double)N_NODES * (double)L2;
    double m = sd[tid] / cnt;
    double var = sd[tid + 16] / cnt - m * m;
    double inv = 1.0 / sqrt(var + 1e-5);
    ws[16 + tid] = (float)((double)g2[tid] * inv);
    ws[32 + tid] = (float)((double)b2[tid] - (double)g2[tid] * inv * m);
  }
}

// ================= K4b v2: vectorized packed-fcw copy + colsum partials (2048 blocks) =================
__global__ __launch_bounds__(256) void dgl_k4b_colsum(const float* __restrict__ fcw,
                                                      float* __restrict__ ws) {
  __shared__ float red[10][96];
  int b = blockIdx.x;                 // 0..2047
  int ch = b >> 3, sub = b & 7;
  int lc = ch & (LCPC - 1);
  int clen = (lc == LCPC - 1) ? (L2 - CHL * (LCPC - 1)) : CHL;
  size_t fb = (size_t)(ch >> 4) * L2 + (size_t)lc * CHL;
  int r0 = sub * CSROWS;
  int r1 = min(clen, r0 + CSROWS);
  unsigned int* bpu = (unsigned int*)(ws + WS_BP);
  int tid = threadIdx.x;
  int e4 = tid % 24, rseg = tid / 24;  // 240 active threads
  if (rseg < 10) {
    float4 cs = make_float4(0.f, 0.f, 0.f, 0.f);
    for (int r = r0 + rseg; r < r1; r += 10) {
      float4 v = *(const float4*)(fcw + (fb + r) * 96 + e4 * 4);
      uint4 p;
      p.x = pack2h(v.x); p.y = pack2h(v.y); p.z = pack2h(v.z); p.w = pack2h(v.w);
      *(uint4*)(bpu + (fb + r) * 96 + e4 * 4) = p;
      cs.x += v.x; cs.y += v.y; cs.z += v.z; cs.w += v.w;
    }
    *(float4*)(&red[rseg][e4 * 4]) = cs;
  }
  __syncthreads();
  if (tid < 96) {
    float t = 0.f;
#pragma unroll
    for (int s = 0; s < 10; ++s) t += red[s][tid];
    ws[WS_CS2 + (size_t)b * 96 + tid] = t;
  }
}

// ================= K5 v14: octet A + reg double-buffer prefetch, batched B staging =================
__global__ __launch_bounds__(320, 2) void dgl_k5_fc(float* __restrict__ ws) {
  __shared__ __align__(16) unsigned short Bh[96 * 192];   // 36 KB
  __shared__ __align__(16) unsigned short Bl[96 * 192];   // 36 KB
  int tid = threadIdx.x;
  int ch = blockIdx.x;                     // 0..255
  int nbase = blockIdx.y * 160;            // n-half
  int c = ch >> 4, lc = ch & (LCPC - 1);
  int clen = (lc == LCPC - 1) ? (L2 - CHL * (LCPC - 1)) : CHL;   // 376 or 342
  size_t fb = (size_t)c * L2 + (size_t)lc * CHL;
  const unsigned int* a2k = (const unsigned int*)(ws + WS_A2);
  const unsigned int* bpu = (const unsigned int*)(ws + WS_BP);
  int wv = tid >> 6, lane = tid & 63;      // wv 0..4
  int m = lane & 15, g = lane >> 4;
  int lc47 = lc * 47;                      // chunk base in octet groups

  f32x4 acc1[2][6], acc2[2][6];
#pragma unroll
  for (int s = 0; s < 2; ++s)
#pragma unroll
    for (int t = 0; t < 6; ++t) {
      acc1[s][t] = (f32x4){0.f, 0.f, 0.f, 0.f};
      acc2[s][t] = (f32x4){0.f, 0.f, 0.f, 0.f};
    }

  unsigned int aa[2][2][8];   // [buf][s][j], all indices compile-time after unroll

#define K5_LOADA(BUF, KSG) do {                                                  \
    int grp_ = lc47 + (KSG) * 4 + g;                                             \
    _Pragma("unroll")                                                            \
    for (int s_ = 0; s_ < 2; ++s_) {                                             \
      int n_ = nbase + (wv + 5 * s_) * 16 + m;                                   \
      const unsigned int* ap_ = a2k + (((size_t)c * NGRP + grp_) * 320 + n_) * 8;\
      uint4 a0_ = *(const uint4*)ap_;                                            \
      uint4 a1_ = *(const uint4*)(ap_ + 4);                                      \
      aa[BUF][s_][0] = a0_.x; aa[BUF][s_][1] = a0_.y;                            \
      aa[BUF][s_][2] = a0_.z; aa[BUF][s_][3] = a0_.w;                            \
      aa[BUF][s_][4] = a1_.x; aa[BUF][s_][5] = a1_.y;                            \
      aa[BUF][s_][6] = a1_.z; aa[BUF][s_][7] = a1_.w;                            \
    }                                                                            \
  } while (0)

  K5_LOADA(0, 0);   // prefetch ks=0 before staging barrier
#pragma unroll 1
  for (int half = 0; half < 2; ++half) {
    int kb0 = half * 192;
    // ---- stage B half: batched loads (full unroll -> all 15 in flight) ----
#pragma unroll
    for (int it = 0; it < 15; ++it) {
      int idx = tid + it * 320;            // < 4608
      if (idx < 4608) {
        int r = idx % 192, eg = idx / 192;
        int rg = kb0 + r;
        uint4 v = (rg < clen) ? *(const uint4*)(bpu + (fb + rg) * 96 + eg * 4)
                              : make_uint4(0u, 0u, 0u, 0u);
        int e0 = eg * 4;
        Bh[swz16(e0 + 0, r)] = (unsigned short)(v.x & 0xFFFFu);
        Bl[swz16(e0 + 0, r)] = (unsigned short)(v.x >> 16);
        Bh[swz16(e0 + 1, r)] = (unsigned short)(v.y & 0xFFFFu);
        Bl[swz16(e0 + 1, r)] = (unsigned short)(v.y >> 16);
        Bh[swz16(e0 + 2, r)] = (unsigned short)(v.z & 0xFFFFu);
        Bl[swz16(e0 + 2, r)] = (unsigned short)(v.z >> 16);
        Bh[swz16(e0 + 3, r)] = (unsigned short)(v.w & 0xFFFFu);
        Bl[swz16(e0 + 3, r)] = (unsigned short)(v.w >> 16);
      }
    }
    __syncthreads();
    // ---- 6 k32 steps, barrier-free, A double-buffer prefetch ----
#pragma unroll
    for (int ks6 = 0; ks6 < 6; ++ks6) {
      int ksg = half * 6 + ks6;            // parity(ksg) == parity(ks6)
      const int cur = ks6 & 1, nxt = (ks6 & 1) ^ 1;
      if (ksg < 11) K5_LOADA(nxt, ksg + 1);   // issue next A before compute
      U4H8 Ahi[2], Alo[2];
#pragma unroll
      for (int s = 0; s < 2; ++s) {
        uint4 a0 = make_uint4(aa[cur][s][0], aa[cur][s][1], aa[cur][s][2], aa[cur][s][3]);
        uint4 a1 = make_uint4(aa[cur][s][4], aa[cur][s][5], aa[cur][s][6], aa[cur][s][7]);
        unpackU4(a0, a1, Ahi[s], Alo[s]);
      }
#pragma unroll
      for (int t = 0; t < 6; ++t) {
        int e = 16 * t + m;
        int kl = ks6 * 32 + 8 * g;
        int kidx = swz16(e, kl);
        U4H8 Bhi, Blo;
        Bhi.u = *(const uint4*)(&Bh[kidx]);
        Blo.u = *(const uint4*)(&Bl[kidx]);
        acc1[0][t] = __builtin_amdgcn_mfma_f32_16x16x32_f16(Ahi[0].h, Bhi.h, acc1[0][t], 0, 0, 0);
        acc2[0][t] = __builtin_amdgcn_mfma_f32_16x16x32_f16(Ahi[0].h, Blo.h, acc2[0][t], 0, 0, 0);
        acc2[0][t] = __builtin_amdgcn_mfma_f32_16x16x32_f16(Alo[0].h, Bhi.h, acc2[0][t], 0, 0, 0);
        acc1[1][t] = __builtin_amdgcn_mfma_f32_16x16x32_f16(Ahi[1].h, Bhi.h, acc1[1][t], 0, 0, 0);
        acc2[1][t] = __builtin_amdgcn_mfma_f32_16x16x32_f16(Ahi[1].h, Blo.h, acc2[1][t], 0, 0, 0);
        acc2[1][t] = __builtin_amdgcn_mfma_f32_16x16x32_f16(Alo[1].h, Bhi.h, acc2[1][t], 0, 0, 0);
      }
    }
    __syncthreads();
  }
#undef K5_LOADA
  float* fp = ws + WS_FP;
#pragma unroll
  for (int s = 0; s < 2; ++s) {
    int nt = wv + 5 * s;
#pragma unroll
    for (int t = 0; t < 6; ++t) {
      int e = 16 * t + m;
      float4 o;
      o.x = acc1[s][t][0] + acc2[s][t][0] * (1.0f / 2048.0f);
      o.y = acc1[s][t][1] + acc2[s][t][1] * (1.0f / 2048.0f);
      o.z = acc1[s][t][2] + acc2[s][t][2] * (1.0f / 2048.0f);
      o.w = acc1[s][t][3] + acc2[s][t][3] * (1.0f / 2048.0f);
      *(float4*)(fp + ((size_t)ch * 96 + e) * 320 + nbase + nt * 16 + 4 * g) = o;
    }
  }
}

// ================= K6a: fp64 channel-group partials (s2-scaled) into dead a2 region =================
__global__ __launch_bounds__(320) void dgl_k6a(float* __restrict__ ws) {
  int e = blockIdx.x, grp = blockIdx.y, n = threadIdx.x;
  const float* fp = ws + WS_FP;
  double* pd = (double*)(ws + WS_A2);
  double a = 0.0;
#pragma unroll
  for (int ci = 0; ci < 2; ++ci) {
    int c = grp * 2 + ci;
    double pc = 0.0;
#pragma unroll
    for (int lcv = 0; lcv < LCPC; ++lcv)
      pc += (double)fp[((size_t)(c * LCPC + lcv) * 96 + e) * 320 + n];
    a += (double)ws[16 + c] * pc;
  }
  pd[((size_t)e * 8 + grp) * 320 + n] = a;
}

// ================= K6b: combine partials + t2*colsum + fcb -> relu -> bn3 =================
__global__ __launch_bounds__(320) void dgl_k6b(const float* __restrict__ fcb,
                                               const float* __restrict__ g3,
                                               const float* __restrict__ b3,
                                               float* __restrict__ ws) {
  int e = blockIdx.x, tid = threadIdx.x;
  __shared__ double csd[16];
  __shared__ double rs[5], rq[5];
  __shared__ float mb[2];
  if (tid < 16) {
    double a = 0.0;
    for (int s = 0; s < LCPC * CSUB; ++s)
      a += (double)ws[WS_CS2 + (size_t)(tid * LCPC * CSUB + s) * 96 + e];
    csd[tid] = a * (double)ws[32 + tid];   // t2[c] * colsum_c[e]
  }
  __syncthreads();
  const double* pd = (const double*)(ws + WS_A2);
  double a = 0.0;
#pragma unroll
  for (int grp = 0; grp < 8; ++grp) a += pd[((size_t)e * 8 + grp) * 320 + tid];
  double cst = 0.0;
#pragma unroll
  for (int c = 0; c < 16; ++c) cst += csd[c];
  float x = fmaxf((float)(a + cst) + fcb[e], 0.f);
  if (tid >= N_NODES) x = 0.f;
  double s = (double)x, q = (double)x * (double)x;
  int wv = tid >> 6, ln = tid & 63;
  for (int o = 32; o; o >>= 1) { s += __shfl_down(s, o, 64); q += __shfl_down(q, o, 64); }
  if (ln == 0) { rs[wv] = s; rq[wv] = q; }
  __syncthreads();
  if (tid == 0) {
    double S = 0.0, Q = 0.0;
    for (int w = 0; w < 5; ++w) { S += rs[w]; Q += rq[w]; }
    double m = S / (double)N_NODES;
    double var = Q / (double)N_NODES - m * m;
    mb[0] = (float)m; mb[1] = (float)(1.0 / sqrt(var + 1e-5));
  }
  __syncthreads();
  if (tid < N_NODES)
    ws[WS_NF + (size_t)tid * 96 + e] = g3[e] * (x - mb[0]) * mb[1] + b3[e];
}

// ================= K7: s_proj / r_proj =================
__global__ __launch_bounds__(192) void dgl_k7_proj(const float* __restrict__ fow,
                                                   float* __restrict__ ws) {
  __shared__ float sh[96];
  int nI = blockIdx.x, tid = threadIdx.x;
  if (tid < 96) sh[tid] = ws[WS_NF + (size_t)nI * 96 + tid];
  __syncthreads();
  int col = tid % 96, half = tid / 96;
  float a = 0.f;
#pragma unroll 8
  for (int d = 0; d < 96; ++d) a = fmaf(sh[d], fow[(size_t)(half * 96 + d) * 96 + col], a);
  ws[(half ? WS_RP : WS_SP) + (size_t)nI * 96 + col] = a;
}

// ================= K8: edge relu + logits + gumbel + hard argmax -> adj =================
__global__ __launch_bounds__(256) void dgl_k8_edge(const float* __restrict__ fob,
                                                   const float* __restrict__ fcatw,
                                                   const float* __restrict__ fcatb,
                                                   const float* __restrict__ unif,
                                                   const float* __restrict__ ws,
                                                   float* __restrict__ out) {
  __shared__ float rp[16][100], sp[16][100], bb[96], wa[96], wb[96];
  int tid = threadIdx.x;
  int i0 = blockIdx.y * 16, j0 = blockIdx.x * 16;
  for (int idx = tid; idx < 16 * 96; idx += 256) {
    int r = idx / 96, e = idx % 96;
    int ii = i0 + r, jj = j0 + r;
    rp[r][e] = (ii < N_NODES) ? ws[WS_RP + (size_t)ii * 96 + e] : 0.f;
    sp[r][e] = (jj < N_NODES) ? ws[WS_SP + (size_t)jj * 96 + e] : 0.f;
  }
  if (tid < 96) { bb[tid] = fob[tid]; wa[tid] = fcatw[2 * tid]; wb[tid] = fcatw[2 * tid + 1]; }
  __syncthreads();
  int il = tid >> 4, jl = tid & 15;
  int i = i0 + il, j = j0 + jl;
  float a0 = 0.f, a1 = 0.f;
#pragma unroll 4
  for (int e = 0; e < 96; ++e) {
    float ef = fmaxf(rp[il][e] + sp[jl][e] + bb[e], 0.f);
    a0 = fmaf(ef, wa[e], a0);
    a1 = fmaf(ef, wb[e], a1);
  }
  if (i < N_NODES && j < N_NODES) {
    size_t ue = ((size_t)i * N_NODES + j) * 2;
    float g0 = -logf(-logf(unif[ue] + 1e-20f) + 1e-20f);
    float g1 = -logf(-logf(unif[ue + 1] + 1e-20f) + 1e-20f);
    float z0 = a0 + fcatb[0] + g0;
    float z1 = a1 + fcatb[1] + g1;
    out[(size_t)i * N_NODES + j] = (i == j) ? 0.f : ((z0 >= z1) ? 1.f : 0.f);
  }
}

extern "C" void kernel_launch(void* const* d_in, const int* in_sizes, int n_in,
                              void* d_out, int out_size, void* d_ws, size_t ws_size,
                              hipStream_t stream) {
  const float* nfeat = (const float*)d_in[1];
  const float* w1    = (const float*)d_in[2];
  const float* b1    = (const float*)d_in[3];
  const float* w2    = (const float*)d_in[4];
  const float* b2    = (const float*)d_in[5];
  const float* g1    = (const float*)d_in[6];
  const float* bb1   = (const float*)d_in[7];
  const float* g2    = (const float*)d_in[8];
  const float* bb2   = (const float*)d_in[9];
  const float* g3    = (const float*)d_in[10];
  const float* bb3   = (const float*)d_in[11];
  const float* fcw   = (const float*)d_in[12];
  const float* fcb   = (const float*)d_in[13];
  const float* fow   = (const float*)d_in[14];
  const float* fob   = (const float*)d_in[15];
  const float* fcatw = (const float*)d_in[16];
  const float* fcatb = (const float*)d_in[17];
  const float* unif  = (const float*)d_in[18];
  float* ws  = (float*)d_ws;
  float* out = (float*)d_out;

  dgl_k0_zero<<<dim3(240), dim3(256), 0, stream>>>(ws);
  dgl_k4b_colsum<<<dim3(K5CH * CSUB), dim3(256), 0, stream>>>(fcw, ws);
  dgl_k1_conv1_stats<<<dim3(375), dim3(320), 0, stream>>>(nfeat, w1, b1, ws);
  dgl_k2_fin1<<<dim3(1), dim3(64), 0, stream>>>(g1, bb1, ws);
  dgl_k3_conv2<<<dim3(K3LB, K3NB), dim3(256), 0, stream>>>(nfeat, w1, b1, w2, b2, ws);
  dgl_k4a<<<dim3(K4ABLK), dim3(512), 0, stream>>>(ws);
  dgl_k4b2_fin<<<dim3(1), dim3(64), 0, stream>>>(g2, bb2, ws);
  dgl_k5_fc<<<dim3(K5CH, 2), dim3(320), 0, stream>>>(ws);
  dgl_k6a<<<dim3(96, 8), dim3(320), 0, stream>>>(ws);
  dgl_k6b<<<dim3(96), dim3(320), 0, stream>>>(fcb, g3, bb3, ws);
  dgl_k7_proj<<<dim3(307), dim3(192), 0, stream>>>(fow, ws);
  dgl_k8_edge<<<dim3(20, 20), dim3(256), 0, stream>>>(fob, fcatw, fcatb, unif, ws, out);
}

// Round 20
// 172.445 us; speedup vs baseline: 1.5613x; 1.5613x over previous
//
#include <hip/hip_runtime.h>
#include <hip/hip_fp16.h>

#define N_NODES 307
#define T_LEN   6000
#define L1      5991
#define L2      5982
#define ED      96
#define FDIM    95712
#define NCH2    16
#define LCPC    16                  // l-chunks per channel
#define CHL     376                 // rows per l-chunk (8-aligned; last = 342)
#define NGRP    753                 // octet groups per channel (6024/8)
#define K5CH    (NCH2 * LCPC)       // 256 K-chunks, channel-pure
#define K3L     32                  // K3 outputs per block
#define K3ZP    43                  // z1 halo rows (32 + 11)
#define K3LB    187                 // ceil(5982/32)
#define K3NB    20
#define K3BLKS  (K3LB * K3NB)       // 3740
#define K4ABLK  40                  // K4a blocks (94 rows each)
#define CSUB    8                   // colsum sub-blocks per chunk
#define CSROWS  47                  // rows per colsum sub-block (8*47=376)

// ---- workspace layout (float/u32 offsets) ----
static const size_t WS_P1 = 256;                    // conv1 stat partials: 375*16
static const size_t WS_P2 = 8192;                   // conv2 stat partials: 3740*32
static const size_t WS_P4D = 127872;                // K4a fp64 partials: 40*32 doubles
static const size_t WS_NF = 155648;                 // node_feat 307*96
static const size_t WS_SP = 188416;                 // s_proj
static const size_t WS_RP = 221184;                 // r_proj
static const size_t WS_A2 = 262144;                 // a2k PACKED u32 [16][753][320][8] (K6a fp64 scratch after K5)
static const size_t WS_FP = 262144 + 30842880ull;   // fc partials: 256*96*320  -> 31,105,024
static const size_t WS_BP = 31105024ull + 7864320ull; // packed fcw u32: 95712*96 -> 38,969,344
static const size_t WS_CS2 = 38969344ull + 9188352ull; // colsum partials: 2048*96 -> 48,157,696
// total = 48,354,304 floats ~= 193.4 MB

typedef _Float16 half8 __attribute__((ext_vector_type(8)));
typedef float f32x4 __attribute__((ext_vector_type(4)));

union U4H8 { uint4 u; half8 h; };

// pack fp32 -> (f16 hi | f16 lo<<16), x ~= hi + lo/2048
__device__ __forceinline__ unsigned int pack2h(float x) {
  __half h = __float2half(x);
  float r = (x - __half2float(h)) * 2048.0f;
  __half l = __float2half(r);
  return (unsigned int)__half_as_ushort(h) | ((unsigned int)__half_as_ushort(l) << 16);
}

// split fp32 -> separate f16 hi / f16 lo words
__device__ __forceinline__ void split2h(float x, unsigned short& ho, unsigned short& lo) {
  __half h = __float2half(x);
  float r = (x - __half2float(h)) * 2048.0f;
  __half l = __float2half(r);
  ho = __half_as_ushort(h);
  lo = __half_as_ushort(l);
}

__device__ __forceinline__ void unpackU4(const uint4& a0, const uint4& a1,
                                         U4H8& hi, U4H8& lo) {
  hi.u = make_uint4((a0.x & 0xFFFFu) | (a0.y << 16), (a0.z & 0xFFFFu) | (a0.w << 16),
                    (a1.x & 0xFFFFu) | (a1.y << 16), (a1.z & 0xFFFFu) | (a1.w << 16));
  lo.u = make_uint4((a0.x >> 16) | (a0.y & 0xFFFF0000u), (a0.z >> 16) | (a0.w & 0xFFFF0000u),
                    (a1.x >> 16) | (a1.y & 0xFFFF0000u), (a1.z >> 16) | (a1.w & 0xFFFF0000u));
}

// K5 B-plane LDS swizzle (u16 index): row e (192 u16), XOR k-chunk by e&7.
__device__ __forceinline__ int swz16(int e, int k) {
  return e * 192 + (k ^ ((e & 7) << 3));
}

// ================= K0: zero a2k pad groups (747..752) =================
__global__ __launch_bounds__(256) void dgl_k0_zero(float* __restrict__ ws) {
  unsigned int* a2k = (unsigned int*)(ws + WS_A2);
  int idx = blockIdx.x * 256 + threadIdx.x;   // 61,440 uint4
  int c = idx / 3840, off4 = idx % 3840;
  unsigned int* p = a2k + (((size_t)c * NGRP + 747) * 320) * 8 + (size_t)off4 * 4;
  *(uint4*)p = make_uint4(0u, 0u, 0u, 0u);
}

// ================= K1: conv1 + relu, channel stats only =================
__global__ __launch_bounds__(320) void dgl_k1_conv1_stats(
    const float* __restrict__ nfeat, const float* __restrict__ w1,
    const float* __restrict__ b1, float* __restrict__ ws) {
  __shared__ float sw1[80], sb1[8];
  __shared__ float sred[5][16];
  int tid = threadIdx.x;
  if (tid < 80) sw1[tid] = w1[tid];
  if (tid < 8)  sb1[tid] = b1[tid];
  __syncthreads();
  int l0 = blockIdx.x * 16;
  int n = tid;
  bool nv = n < N_NODES;
  float xx[26];
#pragma unroll
  for (int j = 0; j < 26; ++j) {
    int t = l0 + j;
    xx[j] = (nv && t < T_LEN) ? nfeat[(size_t)t * N_NODES + n] : 0.f;
  }
  float s[8], q[8];
#pragma unroll
  for (int c = 0; c < 8; ++c) { s[c] = 0.f; q[c] = 0.f; }
#pragma unroll
  for (int dl = 0; dl < 16; ++dl) {
    int l = l0 + dl;
    if (nv && l < L1) {
#pragma unroll
      for (int c = 0; c < 8; ++c) {
        float r = sb1[c];
#pragma unroll
        for (int k = 0; k < 10; ++k) r = fmaf(xx[dl + k], sw1[c * 10 + k], r);
        float z = fmaxf(r, 0.f);
        s[c] += z; q[c] += z * z;
      }
    }
  }
  int wv = tid >> 6, ln = tid & 63;
#pragma unroll
  for (int c = 0; c < 8; ++c) {
    float vs = s[c], vq = q[c];
    for (int o = 32; o; o >>= 1) { vs += __shfl_down(vs, o, 64); vq += __shfl_down(vq, o, 64); }
    if (ln == 0) { sred[wv][c] = vs; sred[wv][8 + c] = vq; }
  }
  __syncthreads();
  if (tid < 16) {
    float t = 0.f;
    for (int w = 0; w < 5; ++w) t += sred[w][tid];
    ws[WS_P1 + (size_t)blockIdx.x * 16 + tid] = t;
  }
}

// ================= K2: finalize bn1 =================
__global__ void dgl_k2_fin1(const float* __restrict__ g1, const float* __restrict__ b1,
                            float* __restrict__ ws) {
  __shared__ double sd[16];
  int tid = threadIdx.x;
  if (tid < 16) {
    double a = 0.0;
    for (int j = 0; j < 375; ++j) a += (double)ws[WS_P1 + (size_t)j * 16 + tid];
    sd[tid] = a;
  }
  __syncthreads();
  if (tid < 8) {
    double cnt = (double)N_NODES * (double)L1;
    double m = sd[tid] / cnt;
    double v = sd[tid + 8] / cnt - m * m;
    double inv = 1.0 / sqrt(v + 1e-5);
    ws[tid]     = (float)((double)g1[tid] * inv);
    ws[8 + tid] = (float)((double)b1[tid] - (double)g1[tid] * inv * m);
  }
}

// ================= K3 (MFMA, split planes, reg sliding-window, octet a2k writes) =================
__global__ __launch_bounds__(256, 4) void dgl_k3_conv2(
    const float* __restrict__ nfeat, const float* __restrict__ w1, const float* __restrict__ b1,
    const float* __restrict__ w2, const float* __restrict__ b2, float* __restrict__ ws) {
  __shared__ __align__(16) unsigned short z1h[K3ZP * 128];  // 11 KB
  __shared__ __align__(16) unsigned short z1l[K3ZP * 128];  // 11 KB
  __shared__ __align__(16) unsigned short w2h[16 * 96], w2l[16 * 96];
  __shared__ float sw1[80], sb1[8], ss1[8], st1[8], sb2v[16];
  __shared__ float wps[4][4][4], wpq[4][4][4];
  int tid = threadIdx.x;
  int l0b = blockIdx.x * K3L, n0 = blockIdx.y * 16;
  unsigned int* a2k = (unsigned int*)(ws + WS_A2);

  if (tid < 80) sw1[tid] = w1[tid];
  if (tid < 8)  { sb1[tid] = b1[tid]; ss1[tid] = ws[tid]; st1[tid] = ws[8 + tid]; }
  if (tid < 16) sb2v[tid] = b2[tid];
  for (int i = tid; i < 16 * 96; i += 256) {
    int c2 = i / 96, kk = i % 96;
    float v = (kk < 80) ? w2[c2 * 80 + (kk & 7) * 10 + (kk >> 3)] : 0.f;
    unsigned short ho, lo;
    split2h(v, ho, lo);
    w2h[i] = ho; w2l[i] = lo;
  }
  __syncthreads();
  // z1 build: thread = (n, cin, half); 31-value x-window in registers, sliding FMA
  {
    int n = tid & 15, cin = (tid >> 4) & 7, hf = tid >> 7;
    int lp0 = hf ? 22 : 0;
    int cnt = hf ? 21 : 22;
    int nld = hf ? 30 : 31;
    int nglob0 = n0 + n;
    bool nv = nglob0 < N_NODES;
    float xx[31];
#pragma unroll
    for (int j = 0; j < 31; ++j) {
      int t = l0b + lp0 + j;
      xx[j] = (j < nld && nv && t < T_LEN) ? nfeat[(size_t)t * N_NODES + nglob0] : 0.f;
    }
    float wr[10];
#pragma unroll
    for (int k = 0; k < 10; ++k) wr[k] = sw1[cin * 10 + k];
    float bb = sb1[cin], sc = ss1[cin], sh = st1[cin];
#pragma unroll
    for (int o = 0; o < 22; ++o) {
      if (o < cnt) {
        float r = bb;
#pragma unroll
        for (int k = 0; k < 10; ++k) r = fmaf(xx[o + k], wr[k], r);
        float z = fmaf(sc, fmaxf(r, 0.f), sh);
        unsigned short ho, lo;
        split2h(z, ho, lo);
        int lp = lp0 + o;
        int idx = lp * 128 + ((n ^ (lp & 15)) << 3) + cin;
        z1h[idx] = ho; z1l[idx] = lo;
      }
    }
  }
  __syncthreads();

  int wv = tid >> 6, lane = tid & 63;
  int m = lane & 15, g = lane >> 4;
  U4H8 Ahi[3], Alo[3];
#pragma unroll
  for (int s = 0; s < 3; ++s) {
    Ahi[s].u = *(const uint4*)(&w2h[m * 96 + 32 * s + 8 * g]);
    Alo[s].u = *(const uint4*)(&w2l[m * 96 + 32 * s + 8 * g]);
  }
  float sv[4] = {0.f, 0.f, 0.f, 0.f}, qv[4] = {0.f, 0.f, 0.f, 0.f};
  unsigned int outw[4][8];
  int nglob = n0 + m;
  bool nok = nglob < N_NODES;
#pragma unroll 1
  for (int li = 0; li < 8; ++li) {
    int ll = 8 * wv + li;
    int lg = l0b + ll;
    f32x4 ac1 = (f32x4){0.f, 0.f, 0.f, 0.f};
    f32x4 ac2 = (f32x4){0.f, 0.f, 0.f, 0.f};
#pragma unroll
    for (int s = 0; s < 3; ++s) {
      int lp = ll + 4 * s + g;
      int bpidx = lp * 128 + ((m ^ (lp & 15)) << 3);
      U4H8 Bhi, Blo;
      Bhi.u = *(const uint4*)(&z1h[bpidx]);
      Blo.u = *(const uint4*)(&z1l[bpidx]);
      ac1 = __builtin_amdgcn_mfma_f32_16x16x32_f16(Ahi[s].h, Bhi.h, ac1, 0, 0, 0);
      ac2 = __builtin_amdgcn_mfma_f32_16x16x32_f16(Ahi[s].h, Blo.h, ac2, 0, 0, 0);
      ac2 = __builtin_amdgcn_mfma_f32_16x16x32_f16(Alo[s].h, Bhi.h, ac2, 0, 0, 0);
    }
#pragma unroll
    for (int r = 0; r < 4; ++r) {
      float v = ac1[r] + ac2[r] * (1.0f / 2048.0f) + sb2v[4 * g + r];
      v = fmaxf(v, 0.f);
      if (!nok || lg >= L2) v = 0.f;
      sv[r] += v; qv[r] += v * v;
      outw[r][li] = pack2h(v);
    }
  }
  // octet write: 8 contiguous u32 per (c2, group, n)
  {
    int grp = (l0b + 8 * wv) >> 3;
#pragma unroll
    for (int r = 0; r < 4; ++r) {
      int c2 = 4 * g + r;
      unsigned int* p = a2k + (((size_t)c2 * NGRP + grp) * 320 + nglob) * 8;
      *(uint4*)p = make_uint4(outw[r][0], outw[r][1], outw[r][2], outw[r][3]);
      *(uint4*)(p + 4) = make_uint4(outw[r][4], outw[r][5], outw[r][6], outw[r][7]);
    }
  }
#pragma unroll
  for (int r = 0; r < 4; ++r) {
    for (int o = 1; o < 16; o <<= 1) {
      sv[r] += __shfl_xor(sv[r], o, 64);
      qv[r] += __shfl_xor(qv[r], o, 64);
    }
  }
  if (m == 0) {
#pragma unroll
    for (int r = 0; r < 4; ++r) { wps[wv][g][r] = sv[r]; wpq[wv][g][r] = qv[r]; }
  }
  __syncthreads();
  if (tid < 32) {
    int c2 = tid & 15; bool isq = tid >= 16;
    int gg = c2 >> 2, rr = c2 & 3;
    float t = 0.f;
    for (int w = 0; w < 4; ++w) t += isq ? wpq[w][gg][rr] : wps[w][gg][rr];
    ws[WS_P2 + ((size_t)blockIdx.y * gridDim.x + blockIdx.x) * 32 + tid] = t;
  }
}

// ================= K4a: tree-reduce conv2 stat partials (fp64) =================
__global__ __launch_bounds__(512) void dgl_k4a(float* __restrict__ ws) {
  __shared__ double red[16][32];
  int tid = threadIdx.x, blk = blockIdx.x;
  int v = tid & 31, p = tid >> 5;   // p 0..15
  double a = 0.0;
#pragma unroll
  for (int k = 0; k < 6; ++k) {
    int idx = p + 16 * k;
    int j = blk * 94 + idx;
    if (idx < 94 && j < K3BLKS) a += (double)ws[WS_P2 + (size_t)j * 32 + v];
  }
  red[p][v] = a;
  __syncthreads();
  if (p == 0) {
    double s = 0.0;
    for (int q = 0; q < 16; ++q) s += red[q][v];
    ((double*)(ws + WS_P4D))[(size_t)blk * 32 + v] = s;
  }
}

// ================= K4b2: finalize bn2 from fp64 partials =================
__global__ void dgl_k4b2_fin(const float* __restrict__ g2, const float* __restrict__ b2,
                             float* __restrict__ ws) {
  __shared__ double sd[32];
  int tid = threadIdx.x;
  if (tid < 32) {
    const double* pd = (const double*)(ws + WS_P4D);
    double s = 0.0;
    for (int b = 0; b < K4ABLK; ++b) s += pd[(size_t)b * 32 + tid];
    sd[tid] = s;
  }
  __syncthreads();
  if (tid < 16) {
    double cnt = (double)N_NODES * (double)L2;
    double m = sd[tid] / cnt;
    double var = sd[tid + 16] / cnt - m * m;
    double inv = 1.0 / sqrt(var + 1e-5);
    ws[16 + tid] = (float)((double)g2[tid] * inv);
    ws[32 + tid] = (float)((double)b2[tid] - (double)g2[tid] * inv * m);
  }
}

// ================= K4b v2: vectorized packed-fcw copy + colsum partials (2048 blocks) =================
__global__ __launch_bounds__(256) void dgl_k4b_colsum(const float* __restrict__ fcw,
                                                      float* __restrict__ ws) {
  __shared__ float red[10][96];
  int b = blockIdx.x;                 // 0..2047
  int ch = b >> 3, sub = b & 7;
  int lc = ch & (LCPC - 1);
  int clen = (lc == LCPC - 1) ? (L2 - CHL * (LCPC - 1)) : CHL;
  size_t fb = (size_t)(ch >> 4) * L2 + (size_t)lc * CHL;
  int r0 = sub * CSROWS;
  int r1 = min(clen, r0 + CSROWS);
  unsigned int* bpu = (unsigned int*)(ws + WS_BP);
  int tid = threadIdx.x;
  int e4 = tid % 24, rseg = tid / 24;  // 240 active threads
  if (rseg < 10) {
    float4 cs = make_float4(0.f, 0.f, 0.f, 0.f);
    for (int r = r0 + rseg; r < r1; r += 10) {
      float4 v = *(const float4*)(fcw + (fb + r) * 96 + e4 * 4);
      uint4 p;
      p.x = pack2h(v.x); p.y = pack2h(v.y); p.z = pack2h(v.z); p.w = pack2h(v.w);
      *(uint4*)(bpu + (fb + r) * 96 + e4 * 4) = p;
      cs.x += v.x; cs.y += v.y; cs.z += v.z; cs.w += v.w;
    }
    *(float4*)(&red[rseg][e4 * 4]) = cs;
  }
  __syncthreads();
  if (tid < 96) {
    float t = 0.f;
#pragma unroll
    for (int s = 0; s < 10; ++s) t += red[s][tid];
    ws[WS_CS2 + (size_t)b * 96 + tid] = t;
  }
}

// ================= K5 v15: 640 threads (10 waves), one n-tile per wave, octet A =================
__global__ __launch_bounds__(640) void dgl_k5_fc(float* __restrict__ ws) {
  __shared__ __align__(16) unsigned short Bh[96 * 192];   // 36 KB
  __shared__ __align__(16) unsigned short Bl[96 * 192];   // 36 KB
  int tid = threadIdx.x;
  int ch = blockIdx.x;                     // 0..255
  int nbase = blockIdx.y * 160;            // n-half
  int c = ch >> 4, lc = ch & (LCPC - 1);
  int clen = (lc == LCPC - 1) ? (L2 - CHL * (LCPC - 1)) : CHL;   // 376 or 342
  size_t fb = (size_t)c * L2 + (size_t)lc * CHL;
  const unsigned int* a2k = (const unsigned int*)(ws + WS_A2);
  const unsigned int* bpu = (const unsigned int*)(ws + WS_BP);
  int wv = tid >> 6, lane = tid & 63;      // wv 0..9 = n-tile
  int m = lane & 15, g = lane >> 4;
  int lc47 = lc * 47;                      // chunk base in octet groups
  int n = nbase + wv * 16 + m;             // this wave's n column

  f32x4 acc1[6], acc2[6];
#pragma unroll
  for (int t = 0; t < 6; ++t) {
    acc1[t] = (f32x4){0.f, 0.f, 0.f, 0.f};
    acc2[t] = (f32x4){0.f, 0.f, 0.f, 0.f};
  }

#pragma unroll 1
  for (int half = 0; half < 2; ++half) {
    int kb0 = half * 192;
    // ---- stage B half (4608 uint4 over 640 threads) ----
#pragma unroll 1
    for (int it = 0; it < 8; ++it) {
      int idx = tid + it * 640;
      if (idx < 4608) {
        int r = idx % 192, eg = idx / 192;
        int rg = kb0 + r;
        uint4 v = (rg < clen) ? *(const uint4*)(bpu + (fb + rg) * 96 + eg * 4)
                              : make_uint4(0u, 0u, 0u, 0u);
        int e0 = eg * 4;
        Bh[swz16(e0 + 0, r)] = (unsigned short)(v.x & 0xFFFFu);
        Bl[swz16(e0 + 0, r)] = (unsigned short)(v.x >> 16);
        Bh[swz16(e0 + 1, r)] = (unsigned short)(v.y & 0xFFFFu);
        Bl[swz16(e0 + 1, r)] = (unsigned short)(v.y >> 16);
        Bh[swz16(e0 + 2, r)] = (unsigned short)(v.z & 0xFFFFu);
        Bl[swz16(e0 + 2, r)] = (unsigned short)(v.z >> 16);
        Bh[swz16(e0 + 3, r)] = (unsigned short)(v.w & 0xFFFFu);
        Bl[swz16(e0 + 3, r)] = (unsigned short)(v.w >> 16);
      }
    }
    __syncthreads();
    // ---- 6 k32 steps, barrier-free ----
#pragma unroll 1
    for (int ks = 0; ks < 6; ++ks) {
      int kbase = kb0 + ks * 32;
      int grp0 = lc47 + (kbase >> 3) + g;
      const unsigned int* ap = a2k + (((size_t)c * NGRP + grp0) * 320 + n) * 8;
      uint4 a0 = *(const uint4*)ap;
      uint4 a1 = *(const uint4*)(ap + 4);
      U4H8 Ahi, Alo;
      unpackU4(a0, a1, Ahi, Alo);
#pragma unroll
      for (int t = 0; t < 6; ++t) {
        int e = 16 * t + m;
        int kl = ks * 32 + 8 * g;
        int kidx = swz16(e, kl);
        U4H8 Bhi, Blo;
        Bhi.u = *(const uint4*)(&Bh[kidx]);
        Blo.u = *(const uint4*)(&Bl[kidx]);
        acc1[t] = __builtin_amdgcn_mfma_f32_16x16x32_f16(Ahi.h, Bhi.h, acc1[t], 0, 0, 0);
        acc2[t] = __builtin_amdgcn_mfma_f32_16x16x32_f16(Ahi.h, Blo.h, acc2[t], 0, 0, 0);
        acc2[t] = __builtin_amdgcn_mfma_f32_16x16x32_f16(Alo.h, Bhi.h, acc2[t], 0, 0, 0);
      }
    }
    __syncthreads();
  }
  float* fp = ws + WS_FP;
#pragma unroll
  for (int t = 0; t < 6; ++t) {
    int e = 16 * t + m;
    float4 o;
    o.x = acc1[t][0] + acc2[t][0] * (1.0f / 2048.0f);
    o.y = acc1[t][1] + acc2[t][1] * (1.0f / 2048.0f);
    o.z = acc1[t][2] + acc2[t][2] * (1.0f / 2048.0f);
    o.w = acc1[t][3] + acc2[t][3] * (1.0f / 2048.0f);
    *(float4*)(fp + ((size_t)ch * 96 + e) * 320 + nbase + wv * 16 + 4 * g) = o;
  }
}

// ================= K6a: fp64 channel-group partials (s2-scaled) into dead a2 region =================
__global__ __launch_bounds__(320) void dgl_k6a(float* __restrict__ ws) {
  int e = blockIdx.x, grp = blockIdx.y, n = threadIdx.x;
  const float* fp = ws + WS_FP;
  double* pd = (double*)(ws + WS_A2);
  double a = 0.0;
#pragma unroll
  for (int ci = 0; ci < 2; ++ci) {
    int c = grp * 2 + ci;
    double pc = 0.0;
#pragma unroll
    for (int lcv = 0; lcv < LCPC; ++lcv)
      pc += (double)fp[((size_t)(c * LCPC + lcv) * 96 + e) * 320 + n];
    a += (double)ws[16 + c] * pc;
  }
  pd[((size_t)e * 8 + grp) * 320 + n] = a;
}

// ================= K6b: combine partials + t2*colsum + fcb -> relu -> bn3 =================
__global__ __launch_bounds__(320) void dgl_k6b(const float* __restrict__ fcb,
                                               const float* __restrict__ g3,
                                               const float* __restrict__ b3,
                                               float* __restrict__ ws) {
  int e = blockIdx.x, tid = threadIdx.x;
  __shared__ double csd[16];
  __shared__ double rs[5], rq[5];
  __shared__ float mb[2];
  if (tid < 16) {
    double a = 0.0;
    for (int s = 0; s < LCPC * CSUB; ++s)
      a += (double)ws[WS_CS2 + (size_t)(tid * LCPC * CSUB + s) * 96 + e];
    csd[tid] = a * (double)ws[32 + tid];   // t2[c] * colsum_c[e]
  }
  __syncthreads();
  const double* pd = (const double*)(ws + WS_A2);
  double a = 0.0;
#pragma unroll
  for (int grp = 0; grp < 8; ++grp) a += pd[((size_t)e * 8 + grp) * 320 + tid];
  double cst = 0.0;
#pragma unroll
  for (int c = 0; c < 16; ++c) cst += csd[c];
  float x = fmaxf((float)(a + cst) + fcb[e], 0.f);
  if (tid >= N_NODES) x = 0.f;
  double s = (double)x, q = (double)x * (double)x;
  int wv = tid >> 6, ln = tid & 63;
  for (int o = 32; o; o >>= 1) { s += __shfl_down(s, o, 64); q += __shfl_down(q, o, 64); }
  if (ln == 0) { rs[wv] = s; rq[wv] = q; }
  __syncthreads();
  if (tid == 0) {
    double S = 0.0, Q = 0.0;
    for (int w = 0; w < 5; ++w) { S += rs[w]; Q += rq[w]; }
    double m = S / (double)N_NODES;
    double var = Q / (double)N_NODES - m * m;
    mb[0] = (float)m; mb[1] = (float)(1.0 / sqrt(var + 1e-5));
  }
  __syncthreads();
  if (tid < N_NODES)
    ws[WS_NF + (size_t)tid * 96 + e] = g3[e] * (x - mb[0]) * mb[1] + b3[e];
}

// ================= K7: s_proj / r_proj =================
__global__ __launch_bounds__(192) void dgl_k7_proj(const float* __restrict__ fow,
                                                   float* __restrict__ ws) {
  __shared__ float sh[96];
  int nI = blockIdx.x, tid = threadIdx.x;
  if (tid < 96) sh[tid] = ws[WS_NF + (size_t)nI * 96 + tid];
  __syncthreads();
  int col = tid % 96, half = tid / 96;
  float a = 0.f;
#pragma unroll 8
  for (int d = 0; d < 96; ++d) a = fmaf(sh[d], fow[(size_t)(half * 96 + d) * 96 + col], a);
  ws[(half ? WS_RP : WS_SP) + (size_t)nI * 96 + col] = a;
}

// ================= K8: edge relu + logits + gumbel + hard argmax -> adj =================
__global__ __launch_bounds__(256) void dgl_k8_edge(const float* __restrict__ fob,
                                                   const float* __restrict__ fcatw,
                                                   const float* __restrict__ fcatb,
                                                   const float* __restrict__ unif,
                                                   const float* __restrict__ ws,
                                                   float* __restrict__ out) {
  __shared__ float rp[16][100], sp[16][100], bb[96], wa[96], wb[96];
  int tid = threadIdx.x;
  int i0 = blockIdx.y * 16, j0 = blockIdx.x * 16;
  for (int idx = tid; idx < 16 * 96; idx += 256) {
    int r = idx / 96, e = idx % 96;
    int ii = i0 + r, jj = j0 + r;
    rp[r][e] = (ii < N_NODES) ? ws[WS_RP + (size_t)ii * 96 + e] : 0.f;
    sp[r][e] = (jj < N_NODES) ? ws[WS_SP + (size_t)jj * 96 + e] : 0.f;
  }
  if (tid < 96) { bb[tid] = fob[tid]; wa[tid] = fcatw[2 * tid]; wb[tid] = fcatw[2 * tid + 1]; }
  __syncthreads();
  int il = tid >> 4, jl = tid & 15;
  int i = i0 + il, j = j0 + jl;
  float a0 = 0.f, a1 = 0.f;
#pragma unroll 4
  for (int e = 0; e < 96; ++e) {
    float ef = fmaxf(rp[il][e] + sp[jl][e] + bb[e], 0.f);
    a0 = fmaf(ef, wa[e], a0);
    a1 = fmaf(ef, wb[e], a1);
  }
  if (i < N_NODES && j < N_NODES) {
    size_t ue = ((size_t)i * N_NODES + j) * 2;
    float g0 = -logf(-logf(unif[ue] + 1e-20f) + 1e-20f);
    float g1 = -logf(-logf(unif[ue + 1] + 1e-20f) + 1e-20f);
    float z0 = a0 + fcatb[0] + g0;
    float z1 = a1 + fcatb[1] + g1;
    out[(size_t)i * N_NODES + j] = (i == j) ? 0.f : ((z0 >= z1) ? 1.f : 0.f);
  }
}

extern "C" void kernel_launch(void* const* d_in, const int* in_sizes, int n_in,
                              void* d_out, int out_size, void* d_ws, size_t ws_size,
                              hipStream_t stream) {
  const float* nfeat = (const float*)d_in[1];
  const float* w1    = (const float*)d_in[2];
  const float* b1    = (const float*)d_in[3];
  const float* w2    = (const float*)d_in[4];
  const float* b2    = (const float*)d_in[5];
  const float* g1    = (const float*)d_in[6];
  const float* bb1   = (const float*)d_in[7];
  const float* g2    = (const float*)d_in[8];
  const float* bb2   = (const float*)d_in[9];
  const float* g3    = (const float*)d_in[10];
  const float* bb3   = (const float*)d_in[11];
  const float* fcw   = (const float*)d_in[12];
  const float* fcb   = (const float*)d_in[13];
  const float* fow   = (const float*)d_in[14];
  const float* fob   = (const float*)d_in[15];
  const float* fcatw = (const float*)d_in[16];
  const float* fcatb = (const float*)d_in[17];
  const float* unif  = (const float*)d_in[18];
  float* ws  = (float*)d_ws;
  float* out = (float*)d_out;

  dgl_k0_zero<<<dim3(240), dim3(256), 0, stream>>>(ws);
  dgl_k4b_colsum<<<dim3(K5CH * CSUB), dim3(256), 0, stream>>>(fcw, ws);
  dgl_k1_conv1_stats<<<dim3(375), dim3(320), 0, stream>>>(nfeat, w1, b1, ws);
  dgl_k2_fin1<<<dim3(1), dim3(64), 0, stream>>>(g1, bb1, ws);
  dgl_k3_conv2<<<dim3(K3LB, K3NB), dim3(256), 0, stream>>>(nfeat, w1, b1, w2, b2, ws);
  dgl_k4a<<<dim3(K4ABLK), dim3(512), 0, stream>>>(ws);
  dgl_k4b2_fin<<<dim3(1), dim3(64), 0, stream>>>(g2, bb2, ws);
  dgl_k5_fc<<<dim3(K5CH, 2), dim3(640), 0, stream>>>(ws);
  dgl_k6a<<<dim3(96, 8), dim3(320), 0, stream>>>(ws);
  dgl_k6b<<<dim3(96), dim3(320), 0, stream>>>(fcb, g3, bb3, ws);
  dgl_k7_proj<<<dim3(307), dim3(192), 0, stream>>>(fow, ws);
  dgl_k8_edge<<<dim3(20, 20), dim3(256), 0, stream>>>(fob, fcatw, fcatb, unif, ws, out);
}